// Round 6
// baseline (2278.471 us; speedup 1.0000x reference)
//
#include <hip/hip_runtime.h>
#include <math.h>

// ---------------------------------------------------------------------------
#define B_ROWS   8192
#define NZ       100
#define NC       2
#define H1       256
#define H2       64
#define FEATN    8192
#define FDIM     1024
#define RROWS    8             // rows per k_main block
#define FF       8             // f values per thread
#define CHUNKF   (256 * FF)    // 2048 f per chunk
#define NCHUNK   (FEATN / CHUNKF)  // 4
#define A1ROWS   16            // rows per k_a1 block
#define A1BLKS   (B_ROWS / A1ROWS)   // 512
#define A2BLKS   (B_ROWS / 4)        // 2048

// ---------------------------------------------------------------------------
// JAX threefry2x32, partitionable, key=(0,42), counter=(0, flat)
__device__ __forceinline__ unsigned rotl32(unsigned v, int r) {
    return (v << r) | (v >> (32 - r));
}
__device__ __forceinline__ unsigned threefry_bits(unsigned lo) {
    const unsigned ks0 = 0u, ks1 = 42u, ks2 = 0x1BD11BDAu ^ 42u;
    unsigned x0 = 0u + ks0;
    unsigned x1 = lo + ks1;
#define TF_R4(a,b,c,d) \
    x0 += x1; x1 = rotl32(x1,a); x1 ^= x0; \
    x0 += x1; x1 = rotl32(x1,b); x1 ^= x0; \
    x0 += x1; x1 = rotl32(x1,c); x1 ^= x0; \
    x0 += x1; x1 = rotl32(x1,d); x1 ^= x0;
    TF_R4(13,15,26,6);  x0 += ks1; x1 += ks2 + 1u;
    TF_R4(17,29,16,24); x0 += ks2; x1 += ks0 + 2u;
    TF_R4(13,15,26,6);  x0 += ks0; x1 += ks1 + 3u;
    TF_R4(17,29,16,24); x0 += ks1; x1 += ks2 + 4u;
    TF_R4(13,15,26,6);  x0 += ks2; x1 += ks0 + 5u;
#undef TF_R4
    return x0 ^ x1;
}
__device__ __forceinline__ float gumbel_g(unsigned flat) {
    unsigned bits = threefry_bits(flat);
    float u  = __uint_as_float((bits >> 9) | 0x3f800000u) - 1.0f;
    float U  = 0.001f * u;
    float t1 = U + 0.001f;
    float L1 = (float)log((double)t1);
    float A  = 0.001f - L1;
    float L2 = (float)log((double)A);
    return -L2;
}

// ---------------------------------------------------------------------------
// K1: a1 = concat(x,y) @ W1 + b1 (fp64 acc) + fused per-block BN partials
__global__ __launch_bounds__(256) void k_a1(
    const float* __restrict__ x, const float* __restrict__ y,
    const float* __restrict__ W1, const float* __restrict__ b1,
    float* __restrict__ a1, double* __restrict__ p1, double* __restrict__ p2)
{
    const int j  = threadIdx.x;
    const int b0 = blockIdx.x * A1ROWS;
    double acc[A1ROWS];
#pragma unroll
    for (int r = 0; r < A1ROWS; ++r) acc[r] = 0.0;
    for (int i = 0; i < NZ; ++i) {
        float w = W1[i * H1 + j];
#pragma unroll
        for (int r = 0; r < A1ROWS; ++r)
            acc[r] += (double)x[(b0 + r) * NZ + i] * (double)w;
    }
#pragma unroll
    for (int i = 0; i < NC; ++i) {
        float w = W1[(NZ + i) * H1 + j];
#pragma unroll
        for (int r = 0; r < A1ROWS; ++r)
            acc[r] += (double)y[(b0 + r) * NC + i] * (double)w;
    }
    double bb = (double)b1[j];
    double s = 0.0, s2 = 0.0;
#pragma unroll
    for (int r = 0; r < A1ROWS; ++r) {
        float v = (float)(acc[r] + bb);
        a1[(b0 + r) * H1 + j] = v;
        double dv = (double)v;
        s += dv; s2 += dv * dv;
    }
    p1[blockIdx.x * H1 + j] = s;
    p2[blockIdx.x * H1 + j] = s2;
}

// ---------------------------------------------------------------------------
// Stats stage 2: reduce nprt per-block partials per column; fold gamma/beta.
__global__ __launch_bounds__(256) void k_stats2(
    const double* __restrict__ p1, const double* __restrict__ p2,
    int nprt, int ncol,
    const float* __restrict__ gamma, const float* __restrict__ beta,
    float* __restrict__ scale, float* __restrict__ shift)
{
    const int j = blockIdx.x, t = threadIdx.x;
    double s = 0.0, s2 = 0.0;
    for (int g = t; g < nprt; g += 256) {
        s  += p1[(size_t)g * ncol + j];
        s2 += p2[(size_t)g * ncol + j];
    }
#pragma unroll
    for (int off = 32; off; off >>= 1) {
        s  += __shfl_xor(s, off);
        s2 += __shfl_xor(s2, off);
    }
    __shared__ double ws1[4], ws2[4];
    if ((t & 63) == 0) { ws1[t >> 6] = s; ws2[t >> 6] = s2; }
    __syncthreads();
    if (t == 0) {
        s  = (ws1[0] + ws1[1]) + (ws1[2] + ws1[3]);
        s2 = (ws2[0] + ws2[1]) + (ws2[2] + ws2[3]);
        double mean = s * (1.0 / B_ROWS);
        double var  = s2 * (1.0 / B_ROWS) - mean * mean;
        double rstd = 1.0 / sqrt(var + 1e-5);
        double sc   = (double)gamma[j] * rstd;
        scale[j] = (float)sc;
        shift[j] = (float)((double)beta[j] - mean * sc);
    }
}

// ---------------------------------------------------------------------------
// K3: a2 = relu(bn(a1)) @ W2 + b2 (fp64 acc) + fused per-block BN partials
__global__ __launch_bounds__(256) void k_a2(
    const float* __restrict__ a1,
    const float* __restrict__ sc1, const float* __restrict__ sh1,
    const float* __restrict__ W2, const float* __restrict__ b2,
    float* __restrict__ a2, double* __restrict__ p1, double* __restrict__ p2)
{
    const int t  = threadIdx.x;
    const int k  = t & 63;
    const int rr = t >> 6;
    const int b  = blockIdx.x * 4 + rr;
    double acc = 0.0;
    for (int j = 0; j < H1; ++j) {
        float h = fmaxf(fmaf(a1[b * H1 + j], sc1[j], sh1[j]), 0.0f);
        acc += (double)h * (double)W2[j * H2 + k];
    }
    float v = (float)(acc + (double)b2[k]);
    a2[b * H2 + k] = v;

    __shared__ double ls[256], ls2[256];
    ls[t]  = (double)v;
    ls2[t] = (double)v * (double)v;
    __syncthreads();
    if (t < 64) {
        double s  = (ls[t]  + ls[t + 64])  + (ls[t + 128]  + ls[t + 192]);
        double s2 = (ls2[t] + ls2[t + 64]) + (ls2[t + 128] + ls2[t + 192]);
        p1[blockIdx.x * H2 + t] = s;
        p2[blockIdx.x * H2 + t] = s2;
    }
}

// ---------------------------------------------------------------------------
// k_main: fully scalarized accumulators + manual 2-stage software pipeline.
#define ACC_DECL \
    float4 aA0=bbA,aA1=bbA,aA2=bbA,aA3=bbA,aA4=bbA,aA5=bbA,aA6=bbA,aA7=bbA; \
    float4 aB0=bbB,aB1=bbB,aB2=bbB,aB3=bbB,aB4=bbB,aB5=bbB,aB6=bbB,aB7=bbB;

#define FMA1(r, hr, wAx, wBx) \
    aA##r.x = fmaf(hr, wAx.x, aA##r.x); aA##r.y = fmaf(hr, wAx.y, aA##r.y); \
    aA##r.z = fmaf(hr, wAx.z, aA##r.z); aA##r.w = fmaf(hr, wAx.w, aA##r.w); \
    aB##r.x = fmaf(hr, wBx.x, aB##r.x); aB##r.y = fmaf(hr, wBx.y, aB##r.y); \
    aB##r.z = fmaf(hr, wBx.z, aB##r.z); aB##r.w = fmaf(hr, wBx.w, aB##r.w);

#define FMAS(wAx, wBx, h0x, h1x) \
    FMA1(0, h0x.x, wAx, wBx) FMA1(1, h0x.y, wAx, wBx) \
    FMA1(2, h0x.z, wAx, wBx) FMA1(3, h0x.w, wAx, wBx) \
    FMA1(4, h1x.x, wAx, wBx) FMA1(5, h1x.y, wAx, wBx) \
    FMA1(6, h1x.z, wAx, wBx) FMA1(7, h1x.w, wAx, wBx)

// Software-pipelined K-sweep over j=0..63: loads for j+1 in flight while
// FMAing j; unroll-by-2 makes the double-buffer rotation free (no v_mov).
// Accumulation order per f is j ascending — bit-identical to prior rounds.
#define SWEEP \
    { \
    const float* wrow = W3 + fbase; \
    float4 wAa = *(const float4*)(wrow); \
    float4 wBa = *(const float4*)(wrow + 4); \
    float4 h0a = *(const float4*)(&h2T[0][0]); \
    float4 h1a = *(const float4*)(&h2T[0][4]); \
    float4 wAb, wBb, h0b, h1b; \
    _Pragma("unroll 1") \
    for (int j = 0; j < 62; j += 2) { \
        const float* w1 = wrow + FEATN; \
        wAb = *(const float4*)(w1); wBb = *(const float4*)(w1 + 4); \
        h0b = *(const float4*)(&h2T[j+1][0]); h1b = *(const float4*)(&h2T[j+1][4]); \
        FMAS(wAa, wBa, h0a, h1a) \
        const float* w2 = wrow + 2 * FEATN; \
        wAa = *(const float4*)(w2); wBa = *(const float4*)(w2 + 4); \
        h0a = *(const float4*)(&h2T[j+2][0]); h1a = *(const float4*)(&h2T[j+2][4]); \
        FMAS(wAb, wBb, h0b, h1b) \
        wrow = w2; \
    } \
    { \
        const float* w1 = wrow + FEATN; \
        wAb = *(const float4*)(w1); wBb = *(const float4*)(w1 + 4); \
        h0b = *(const float4*)(&h2T[63][0]); h1b = *(const float4*)(&h2T[63][4]); \
        FMAS(wAa, wBa, h0a, h1a) \
        FMAS(wAb, wBb, h0b, h1b) \
    } \
    }

#define ROWMAX(r) { \
    float m = fmaxf(fmaxf(fmaxf(aA##r.x, aA##r.y), fmaxf(aA##r.z, aA##r.w)), \
                    fmaxf(fmaxf(aB##r.x, aB##r.y), fmaxf(aB##r.z, aB##r.w))); \
    m = fmaxf(m, __shfl_xor(m, 32)); m = fmaxf(m, __shfl_xor(m, 16)); \
    m = fmaxf(m, __shfl_xor(m, 8));  m = fmaxf(m, __shfl_xor(m, 4)); \
    m = fmaxf(m, __shfl_xor(m, 2));  m = fmaxf(m, __shfl_xor(m, 1)); \
    if (lane == 0) cm[fc][r][wv] = m; }

#define CHK(r, vexpr, q) { \
    float vv = (vexpr); \
    if (vv >= th) { \
        int f = fbase + q; \
        float scv = vv + gumbel_g((unsigned)(b0 + r) * (unsigned)FEATN + (unsigned)f); \
        if (scv > bS##r || (scv == bS##r && f < bI##r)) { bS##r = scv; bI##r = f; } \
    } }

#define CAND(r) if (qmask & (1u << r)) { \
    const float th = thrS[r]; \
    CHK(r, aA##r.x, 0) CHK(r, aA##r.y, 1) CHK(r, aA##r.z, 2) CHK(r, aA##r.w, 3) \
    CHK(r, aB##r.x, 4) CHK(r, aB##r.y, 5) CHK(r, aB##r.z, 6) CHK(r, aB##r.w, 7) }

#define REDROW(r) { \
    float v = bS##r; int ix = bI##r; \
    _Pragma("unroll") \
    for (int off = 32; off; off >>= 1) { \
        float ov = __shfl_xor(v, off); \
        int   oi = __shfl_xor(ix, off); \
        if (ov > v || (ov == v && oi < ix)) { v = ov; ix = oi; } \
    } \
    if (lane == 0) { redS[r][wv] = v; redI[r][wv] = ix; } }

// K5: pass A = rowmax of logits; pass B = recompute only qualifying
//     (chunk,wave) cells with gumbel; gather codebook row.
// __launch_bounds__(256,4): 4 waves/EU — VGPR cap 128, exactly matches the
// 4-blocks/CU the 1024-block grid provides; frees regs for the pipeline.
__global__ __launch_bounds__(256, 4) void k_main(
    const float* __restrict__ a2,
    const float* __restrict__ sc2, const float* __restrict__ sh2,
    const float* __restrict__ W3, const float* __restrict__ b3,
    const float* __restrict__ codebook, float* __restrict__ out)
{
    const int t    = threadIdx.x;
    const int wv   = t >> 6;
    const int lane = t & 63;
    const int b0   = blockIdx.x * RROWS;

    __shared__ __align__(16) float h2T[64][RROWS];   // [j][r], 2 KB
    __shared__ float cm[NCHUNK][RROWS][4];
    __shared__ float thrS[RROWS];
    __shared__ float redS[RROWS][4];
    __shared__ int   redI[RROWS][4];
    __shared__ int   rowInd[RROWS];

    // h2 = relu(bn(a2)) for our rows — strided: 512 elements, 256 threads
    for (int q = t; q < RROWS * 64; q += 256) {
        int j = q >> 3, r = q & 7;
        float v = a2[(b0 + r) * H2 + j];
        h2T[j][r] = fmaxf(fmaf(v, sc2[j], sh2[j]), 0.0f);
    }
    __syncthreads();

    // ---- Pass A: rowmax of logits ----
    for (int fc = 0; fc < NCHUNK; ++fc) {
        const int fbase = fc * CHUNKF + t * FF;
        const float4 bbA = *(const float4*)(b3 + fbase);
        const float4 bbB = *(const float4*)(b3 + fbase + 4);
        ACC_DECL
        SWEEP
        ROWMAX(0) ROWMAX(1) ROWMAX(2) ROWMAX(3)
        ROWMAX(4) ROWMAX(5) ROWMAX(6) ROWMAX(7)
    }
    __syncthreads();
    if (t < RROWS) {
        float m = -1e30f;
        for (int fc = 0; fc < NCHUNK; ++fc)
            for (int w = 0; w < 4; ++w) m = fmaxf(m, cm[fc][t][w]);
        thrS[t] = m - 0.1068f;    // gumbel range 0.10597 + fp32 slack
    }
    __syncthreads();

    // ---- Pass B: recompute only qualifying (chunk, wave) cells ----
    float bS0=-1e30f,bS1=-1e30f,bS2=-1e30f,bS3=-1e30f,
          bS4=-1e30f,bS5=-1e30f,bS6=-1e30f,bS7=-1e30f;
    int   bI0=0,bI1=0,bI2=0,bI3=0,bI4=0,bI5=0,bI6=0,bI7=0;

    for (int fc = 0; fc < NCHUNK; ++fc) {
        unsigned qmask = 0;
#pragma unroll
        for (int r = 0; r < RROWS; ++r)
            if (cm[fc][r][wv] >= thrS[r]) qmask |= (1u << r);
        if (qmask == 0) continue;                 // wave-uniform skip

        const int fbase = fc * CHUNKF + t * FF;
        const float4 bbA = *(const float4*)(b3 + fbase);
        const float4 bbB = *(const float4*)(b3 + fbase + 4);
        ACC_DECL
        SWEEP
        CAND(0) CAND(1) CAND(2) CAND(3)
        CAND(4) CAND(5) CAND(6) CAND(7)
    }

    // reduce best (val, idx) across wave, then across waves
    REDROW(0) REDROW(1) REDROW(2) REDROW(3)
    REDROW(4) REDROW(5) REDROW(6) REDROW(7)
    __syncthreads();
    if (t < RROWS) {
        float v = -1e30f; int ix = 0;
        for (int w = 0; w < 4; ++w) {
            float ov = redS[t][w]; int oi = redI[t][w];
            if (ov > v || (ov == v && oi < ix && ov > -1e29f)) { v = ov; ix = oi; }
        }
        rowInd[t] = ix & (FEATN - 1);   // hard guarantee: in-bounds gather
    }
    __syncthreads();

    // out[b,:] = codebook[ind,:]   (z_st == one-hot to ~1e-7)
    for (int r = 0; r < RROWS; ++r) {
        const int ind = rowInd[r];
        const float4* src = (const float4*)(codebook + (size_t)ind * FDIM);
        float4*       dst = (float4*)(out + (size_t)(b0 + r) * FDIM);
        dst[t] = src[t];
    }
}

// ---------------------------------------------------------------------------
extern "C" void kernel_launch(void* const* d_in, const int* in_sizes, int n_in,
                              void* d_out, int out_size, void* d_ws, size_t ws_size,
                              hipStream_t stream)
{
    const float* x   = (const float*)d_in[0];
    const float* y   = (const float*)d_in[1];
    const float* W1  = (const float*)d_in[2];
    const float* b1  = (const float*)d_in[3];
    const float* g1  = (const float*)d_in[4];
    const float* be1 = (const float*)d_in[5];
    const float* W2  = (const float*)d_in[6];
    const float* b2  = (const float*)d_in[7];
    const float* g2  = (const float*)d_in[8];
    const float* be2 = (const float*)d_in[9];
    const float* W3  = (const float*)d_in[10];
    const float* b3  = (const float*)d_in[11];
    const float* cb  = (const float*)d_in[12];
    float* out = (float*)d_out;

    float* ws  = (float*)d_ws;
    float* a1  = ws;                          // 8192*256 f32 (8 MB)
    float* a2  = a1 + B_ROWS * H1;            // 8192*64 f32 (2 MB)
    float* sc1 = a2 + B_ROWS * H2;
    float* sh1 = sc1 + H1;
    float* sc2 = sh1 + H1;
    float* sh2 = sc2 + H2;
    double* p1 = (double*)(sh2 + H2);         // 131072 f64 (1 MB), 8B-aligned
    double* p2 = p1 + A2BLKS * H2;            // 131072 f64 (1 MB)
    // total ws ≈ 12.1 MB

    k_a1    <<<A1BLKS, 256, 0, stream>>>(x, y, W1, b1, a1, p1, p2);
    k_stats2<<<H1, 256, 0, stream>>>(p1, p2, A1BLKS, H1, g1, be1, sc1, sh1);
    k_a2    <<<A2BLKS, 256, 0, stream>>>(a1, sc1, sh1, W2, b2, a2, p1, p2);
    k_stats2<<<H2, 256, 0, stream>>>(p1, p2, A2BLKS, H2, g2, be2, sc2, sh2);
    k_main  <<<B_ROWS / RROWS, 256, 0, stream>>>(a2, sc2, sh2, W3, b3, cb, out);
}

// Round 7
// 465.377 us; speedup vs baseline: 4.8960x; 4.8960x over previous
//
#include <hip/hip_runtime.h>
#include <math.h>

// ---------------------------------------------------------------------------
#define B_ROWS   8192
#define NZ       100
#define NC       2
#define H1       256
#define H2       64
#define FEATN    8192
#define FDIM     1024
#define RROWS    8             // rows per k_main block
#define FF       8             // f values per thread
#define CHUNKF   (256 * FF)    // 2048 f per chunk
#define NCHUNK   (FEATN / CHUNKF)  // 4
#define A1ROWS   16            // rows per k_a1 block
#define A1BLKS   (B_ROWS / A1ROWS)   // 512
#define A2BLKS   (B_ROWS / 4)        // 2048

// ---------------------------------------------------------------------------
// JAX threefry2x32, partitionable, key=(0,42), counter=(0, flat)
__device__ __forceinline__ unsigned rotl32(unsigned v, int r) {
    return (v << r) | (v >> (32 - r));
}
__device__ __forceinline__ unsigned threefry_bits(unsigned lo) {
    const unsigned ks0 = 0u, ks1 = 42u, ks2 = 0x1BD11BDAu ^ 42u;
    unsigned x0 = 0u + ks0;
    unsigned x1 = lo + ks1;
#define TF_R4(a,b,c,d) \
    x0 += x1; x1 = rotl32(x1,a); x1 ^= x0; \
    x0 += x1; x1 = rotl32(x1,b); x1 ^= x0; \
    x0 += x1; x1 = rotl32(x1,c); x1 ^= x0; \
    x0 += x1; x1 = rotl32(x1,d); x1 ^= x0;
    TF_R4(13,15,26,6);  x0 += ks1; x1 += ks2 + 1u;
    TF_R4(17,29,16,24); x0 += ks2; x1 += ks0 + 2u;
    TF_R4(13,15,26,6);  x0 += ks0; x1 += ks1 + 3u;
    TF_R4(17,29,16,24); x0 += ks1; x1 += ks2 + 4u;
    TF_R4(13,15,26,6);  x0 += ks2; x1 += ks0 + 5u;
#undef TF_R4
    return x0 ^ x1;
}
__device__ __forceinline__ float gumbel_g(unsigned flat) {
    unsigned bits = threefry_bits(flat);
    float u  = __uint_as_float((bits >> 9) | 0x3f800000u) - 1.0f;
    float U  = 0.001f * u;
    float t1 = U + 0.001f;
    float L1 = (float)log((double)t1);
    float A  = 0.001f - L1;
    float L2 = (float)log((double)A);
    return -L2;
}

// ---------------------------------------------------------------------------
// K1: a1 = concat(x,y) @ W1 + b1 (fp64 acc) + fused per-block BN partials
__global__ __launch_bounds__(256) void k_a1(
    const float* __restrict__ x, const float* __restrict__ y,
    const float* __restrict__ W1, const float* __restrict__ b1,
    float* __restrict__ a1, double* __restrict__ p1, double* __restrict__ p2)
{
    const int j  = threadIdx.x;
    const int b0 = blockIdx.x * A1ROWS;
    double acc[A1ROWS];
#pragma unroll
    for (int r = 0; r < A1ROWS; ++r) acc[r] = 0.0;
    for (int i = 0; i < NZ; ++i) {
        float w = W1[i * H1 + j];
#pragma unroll
        for (int r = 0; r < A1ROWS; ++r)
            acc[r] += (double)x[(b0 + r) * NZ + i] * (double)w;
    }
#pragma unroll
    for (int i = 0; i < NC; ++i) {
        float w = W1[(NZ + i) * H1 + j];
#pragma unroll
        for (int r = 0; r < A1ROWS; ++r)
            acc[r] += (double)y[(b0 + r) * NC + i] * (double)w;
    }
    double bb = (double)b1[j];
    double s = 0.0, s2 = 0.0;
#pragma unroll
    for (int r = 0; r < A1ROWS; ++r) {
        float v = (float)(acc[r] + bb);
        a1[(b0 + r) * H1 + j] = v;
        double dv = (double)v;
        s += dv; s2 += dv * dv;
    }
    p1[blockIdx.x * H1 + j] = s;
    p2[blockIdx.x * H1 + j] = s2;
}

// ---------------------------------------------------------------------------
// Stats stage 2: reduce nprt per-block partials per column; fold gamma/beta.
__global__ __launch_bounds__(256) void k_stats2(
    const double* __restrict__ p1, const double* __restrict__ p2,
    int nprt, int ncol,
    const float* __restrict__ gamma, const float* __restrict__ beta,
    float* __restrict__ scale, float* __restrict__ shift)
{
    const int j = blockIdx.x, t = threadIdx.x;
    double s = 0.0, s2 = 0.0;
    for (int g = t; g < nprt; g += 256) {
        s  += p1[(size_t)g * ncol + j];
        s2 += p2[(size_t)g * ncol + j];
    }
#pragma unroll
    for (int off = 32; off; off >>= 1) {
        s  += __shfl_xor(s, off);
        s2 += __shfl_xor(s2, off);
    }
    __shared__ double ws1[4], ws2[4];
    if ((t & 63) == 0) { ws1[t >> 6] = s; ws2[t >> 6] = s2; }
    __syncthreads();
    if (t == 0) {
        s  = (ws1[0] + ws1[1]) + (ws1[2] + ws1[3]);
        s2 = (ws2[0] + ws2[1]) + (ws2[2] + ws2[3]);
        double mean = s * (1.0 / B_ROWS);
        double var  = s2 * (1.0 / B_ROWS) - mean * mean;
        double rstd = 1.0 / sqrt(var + 1e-5);
        double sc   = (double)gamma[j] * rstd;
        scale[j] = (float)sc;
        shift[j] = (float)((double)beta[j] - mean * sc);
    }
}

// ---------------------------------------------------------------------------
// K3: a2 = relu(bn(a1)) @ W2 + b2 (fp64 acc) + fused per-block BN partials
__global__ __launch_bounds__(256) void k_a2(
    const float* __restrict__ a1,
    const float* __restrict__ sc1, const float* __restrict__ sh1,
    const float* __restrict__ W2, const float* __restrict__ b2,
    float* __restrict__ a2, double* __restrict__ p1, double* __restrict__ p2)
{
    const int t  = threadIdx.x;
    const int k  = t & 63;
    const int rr = t >> 6;
    const int b  = blockIdx.x * 4 + rr;
    double acc = 0.0;
    for (int j = 0; j < H1; ++j) {
        float h = fmaxf(fmaf(a1[b * H1 + j], sc1[j], sh1[j]), 0.0f);
        acc += (double)h * (double)W2[j * H2 + k];
    }
    float v = (float)(acc + (double)b2[k]);
    a2[b * H2 + k] = v;

    __shared__ double ls[256], ls2[256];
    ls[t]  = (double)v;
    ls2[t] = (double)v * (double)v;
    __syncthreads();
    if (t < 64) {
        double s  = (ls[t]  + ls[t + 64])  + (ls[t + 128]  + ls[t + 192]);
        double s2 = (ls2[t] + ls2[t + 64]) + (ls2[t + 128] + ls2[t + 192]);
        p1[blockIdx.x * H2 + t] = s;
        p2[blockIdx.x * H2 + t] = s2;
    }
}

// ---------------------------------------------------------------------------
// k_main: scalarized accumulators; plain j-loop (unroll 2, scheduler hoists
// loads); fine-grained (row, 8-f-segment) pruning for pass B.
#define ACC_DECL \
    float4 aA0=bbA,aA1=bbA,aA2=bbA,aA3=bbA,aA4=bbA,aA5=bbA,aA6=bbA,aA7=bbA; \
    float4 aB0=bbB,aB1=bbB,aB2=bbB,aB3=bbB,aB4=bbB,aB5=bbB,aB6=bbB,aB7=bbB;

#define FMA1(r, hr, wAx, wBx) \
    aA##r.x = fmaf(hr, wAx.x, aA##r.x); aA##r.y = fmaf(hr, wAx.y, aA##r.y); \
    aA##r.z = fmaf(hr, wAx.z, aA##r.z); aA##r.w = fmaf(hr, wAx.w, aA##r.w); \
    aB##r.x = fmaf(hr, wBx.x, aB##r.x); aB##r.y = fmaf(hr, wBx.y, aB##r.y); \
    aB##r.z = fmaf(hr, wBx.z, aB##r.z); aB##r.w = fmaf(hr, wBx.w, aB##r.w);

#define FMAS(wAx, wBx, h0x, h1x) \
    FMA1(0, h0x.x, wAx, wBx) FMA1(1, h0x.y, wAx, wBx) \
    FMA1(2, h0x.z, wAx, wBx) FMA1(3, h0x.w, wAx, wBx) \
    FMA1(4, h1x.x, wAx, wBx) FMA1(5, h1x.y, wAx, wBx) \
    FMA1(6, h1x.z, wAx, wBx) FMA1(7, h1x.w, wAx, wBx)

// per-row max of this thread's 8 f-values -> fineS (for pass-B pruning)
// and wave-reduced chunk max -> cm (for threshold).
#define ROWMAX(r) { \
    float m = fmaxf(fmaxf(fmaxf(aA##r.x, aA##r.y), fmaxf(aA##r.z, aA##r.w)), \
                    fmaxf(fmaxf(aB##r.x, aB##r.y), fmaxf(aB##r.z, aB##r.w))); \
    fineS[r][fc][t] = m; \
    m = fmaxf(m, __shfl_xor(m, 32)); m = fmaxf(m, __shfl_xor(m, 16)); \
    m = fmaxf(m, __shfl_xor(m, 8));  m = fmaxf(m, __shfl_xor(m, 4)); \
    m = fmaxf(m, __shfl_xor(m, 2));  m = fmaxf(m, __shfl_xor(m, 1)); \
    if (lane == 0) cm[fc][r][wv] = m; }

#define CHK(r, vexpr, q) { \
    float vv = (vexpr); \
    if (vv >= th) { \
        int f = fbase + q; \
        float scv = vv + gumbel_g((unsigned)(b0 + r) * (unsigned)FEATN + (unsigned)f); \
        if (scv > bS##r || (scv == bS##r && f < bI##r)) { bS##r = scv; bI##r = f; } \
    } }

// Pass-B: recompute ONE row's 8-f dot (bit-identical order) if its fine
// segment max passes the threshold. Rare (~10 cells per block).
#define CANDR(r) if (fineS[r][fc][t] >= thrS[r]) { \
    const float4 bbA = *(const float4*)(b3 + fbase); \
    const float4 bbB = *(const float4*)(b3 + fbase + 4); \
    float4 aA = bbA, aB = bbB; \
    const float* wrow = W3 + fbase; \
    _Pragma("unroll 2") \
    for (int j = 0; j < 64; ++j) { \
        const float4 wA = *(const float4*)(wrow); \
        const float4 wB = *(const float4*)(wrow + 4); \
        const float hr = h2T[j][r]; \
        aA.x = fmaf(hr, wA.x, aA.x); aA.y = fmaf(hr, wA.y, aA.y); \
        aA.z = fmaf(hr, wA.z, aA.z); aA.w = fmaf(hr, wA.w, aA.w); \
        aB.x = fmaf(hr, wB.x, aB.x); aB.y = fmaf(hr, wB.y, aB.y); \
        aB.z = fmaf(hr, wB.z, aB.z); aB.w = fmaf(hr, wB.w, aB.w); \
        wrow += FEATN; \
    } \
    const float th = thrS[r]; \
    CHK(r, aA.x, 0) CHK(r, aA.y, 1) CHK(r, aA.z, 2) CHK(r, aA.w, 3) \
    CHK(r, aB.x, 4) CHK(r, aB.y, 5) CHK(r, aB.z, 6) CHK(r, aB.w, 7) }

#define REDROW(r) { \
    float v = bS##r; int ix = bI##r; \
    _Pragma("unroll") \
    for (int off = 32; off; off >>= 1) { \
        float ov = __shfl_xor(v, off); \
        int   oi = __shfl_xor(ix, off); \
        if (ov > v || (ov == v && oi < ix)) { v = ov; ix = oi; } \
    } \
    if (lane == 0) { redS[r][wv] = v; redI[r][wv] = ix; } }

// amdgpu_waves_per_eu(4,4): min AND max — budget 128 VGPR, and (per R6's
// post-mortem) the max stops the allocator from chasing 8-wave occupancy
// by spilling. Grid 1024 = 4 blocks/CU = 4 waves/EU, matching exactly.
__global__ __launch_bounds__(256)
__attribute__((amdgpu_waves_per_eu(4, 4)))
void k_main(
    const float* __restrict__ a2,
    const float* __restrict__ sc2, const float* __restrict__ sh2,
    const float* __restrict__ W3, const float* __restrict__ b3,
    const float* __restrict__ codebook, float* __restrict__ out)
{
    const int t    = threadIdx.x;
    const int wv   = t >> 6;
    const int lane = t & 63;
    const int b0   = blockIdx.x * RROWS;

    __shared__ __align__(16) float h2T[64][RROWS];   // [j][r], 2 KB
    __shared__ float fineS[RROWS][NCHUNK][256];      // 32 KB segment maxima
    __shared__ float cm[NCHUNK][RROWS][4];
    __shared__ float thrS[RROWS];
    __shared__ float redS[RROWS][4];
    __shared__ int   redI[RROWS][4];
    __shared__ int   rowInd[RROWS];

    // h2 = relu(bn(a2)) for our rows — strided: 512 elements, 256 threads
    for (int q = t; q < RROWS * 64; q += 256) {
        int j = q >> 3, r = q & 7;
        float v = a2[(b0 + r) * H2 + j];
        h2T[j][r] = fmaxf(fmaf(v, sc2[j], sh2[j]), 0.0f);
    }
    __syncthreads();

    // ---- Pass A: rowmax of logits + fine segment maxima ----
    for (int fc = 0; fc < NCHUNK; ++fc) {
        const int fbase = fc * CHUNKF + t * FF;
        const float4 bbA = *(const float4*)(b3 + fbase);
        const float4 bbB = *(const float4*)(b3 + fbase + 4);
        ACC_DECL
        const float* wrow = W3 + fbase;
#pragma unroll 2
        for (int j = 0; j < 64; ++j) {
            const float4 wA = *(const float4*)(wrow);
            const float4 wB = *(const float4*)(wrow + 4);
            const float4 h0 = *(const float4*)(&h2T[j][0]);
            const float4 h1 = *(const float4*)(&h2T[j][4]);
            FMAS(wA, wB, h0, h1)
            wrow += FEATN;
        }
        ROWMAX(0) ROWMAX(1) ROWMAX(2) ROWMAX(3)
        ROWMAX(4) ROWMAX(5) ROWMAX(6) ROWMAX(7)
    }
    __syncthreads();
    if (t < RROWS) {
        float m = -1e30f;
        for (int fc = 0; fc < NCHUNK; ++fc)
            for (int w = 0; w < 4; ++w) m = fmaxf(m, cm[fc][t][w]);
        thrS[t] = m - 0.1068f;    // gumbel range 0.10581 + fp32 slack
    }
    __syncthreads();

    // ---- Pass B: recompute only qualifying (row, 8-f-segment) cells ----
    float bS0=-1e30f,bS1=-1e30f,bS2=-1e30f,bS3=-1e30f,
          bS4=-1e30f,bS5=-1e30f,bS6=-1e30f,bS7=-1e30f;
    int   bI0=0,bI1=0,bI2=0,bI3=0,bI4=0,bI5=0,bI6=0,bI7=0;

    for (int fc = 0; fc < NCHUNK; ++fc) {
        const int fbase = fc * CHUNKF + t * FF;
        CANDR(0) CANDR(1) CANDR(2) CANDR(3)
        CANDR(4) CANDR(5) CANDR(6) CANDR(7)
    }

    // reduce best (val, idx) across wave, then across waves
    REDROW(0) REDROW(1) REDROW(2) REDROW(3)
    REDROW(4) REDROW(5) REDROW(6) REDROW(7)
    __syncthreads();
    if (t < RROWS) {
        float v = -1e30f; int ix = 0;
        for (int w = 0; w < 4; ++w) {
            float ov = redS[t][w]; int oi = redI[t][w];
            if (ov > v || (ov == v && oi < ix && ov > -1e29f)) { v = ov; ix = oi; }
        }
        rowInd[t] = ix & (FEATN - 1);   // hard guarantee: in-bounds gather
    }
    __syncthreads();

    // out[b,:] = codebook[ind,:]   (z_st == one-hot to ~1e-7)
    for (int r = 0; r < RROWS; ++r) {
        const int ind = rowInd[r];
        const float4* src = (const float4*)(codebook + (size_t)ind * FDIM);
        float4*       dst = (float4*)(out + (size_t)(b0 + r) * FDIM);
        dst[t] = src[t];
    }
}

// ---------------------------------------------------------------------------
extern "C" void kernel_launch(void* const* d_in, const int* in_sizes, int n_in,
                              void* d_out, int out_size, void* d_ws, size_t ws_size,
                              hipStream_t stream)
{
    const float* x   = (const float*)d_in[0];
    const float* y   = (const float*)d_in[1];
    const float* W1  = (const float*)d_in[2];
    const float* b1  = (const float*)d_in[3];
    const float* g1  = (const float*)d_in[4];
    const float* be1 = (const float*)d_in[5];
    const float* W2  = (const float*)d_in[6];
    const float* b2  = (const float*)d_in[7];
    const float* g2  = (const float*)d_in[8];
    const float* be2 = (const float*)d_in[9];
    const float* W3  = (const float*)d_in[10];
    const float* b3  = (const float*)d_in[11];
    const float* cb  = (const float*)d_in[12];
    float* out = (float*)d_out;

    float* ws  = (float*)d_ws;
    float* a1  = ws;                          // 8192*256 f32 (8 MB)
    float* a2  = a1 + B_ROWS * H1;            // 8192*64 f32 (2 MB)
    float* sc1 = a2 + B_ROWS * H2;
    float* sh1 = sc1 + H1;
    float* sc2 = sh1 + H1;
    float* sh2 = sc2 + H2;
    double* p1 = (double*)(sh2 + H2);         // 131072 f64 (1 MB), 8B-aligned
    double* p2 = p1 + A2BLKS * H2;            // 131072 f64 (1 MB)
    // total ws ≈ 12.1 MB

    k_a1    <<<A1BLKS, 256, 0, stream>>>(x, y, W1, b1, a1, p1, p2);
    k_stats2<<<H1, 256, 0, stream>>>(p1, p2, A1BLKS, H1, g1, be1, sc1, sh1);
    k_a2    <<<A2BLKS, 256, 0, stream>>>(a1, sc1, sh1, W2, b2, a2, p1, p2);
    k_stats2<<<H2, 256, 0, stream>>>(p1, p2, A2BLKS, H2, g2, be2, sc2, sh2);
    k_main  <<<B_ROWS / RROWS, 256, 0, stream>>>(a2, sc2, sh2, W3, b3, cb, out);
}

// Round 8
// 420.226 us; speedup vs baseline: 5.4220x; 1.1074x over previous
//
#include <hip/hip_runtime.h>
#include <math.h>

// ---------------------------------------------------------------------------
#define B_ROWS   8192
#define NZ       100
#define NC       2
#define H1       256
#define H2       64
#define FEATN    8192
#define FDIM     1024
#define RROWS    16            // rows per k_main block = MFMA M
#define NTILE    (FEATN / 16)  // 512 16-col MFMA tiles
#define A1ROWS   16
#define A1BLKS   (B_ROWS / A1ROWS)   // 512
#define CONVBLKS 256                 // w3 conversion blocks fused into k_a1
#define A2BLKS   (B_ROWS / 4)        // 2048

typedef __attribute__((ext_vector_type(8))) short short8;
typedef __attribute__((ext_vector_type(4))) float f32x4;

// ---------------------------------------------------------------------------
// JAX threefry2x32, partitionable, key=(0,42), counter=(0, flat)
__device__ __forceinline__ unsigned rotl32(unsigned v, int r) {
    return (v << r) | (v >> (32 - r));
}
__device__ __forceinline__ unsigned threefry_bits(unsigned lo) {
    const unsigned ks0 = 0u, ks1 = 42u, ks2 = 0x1BD11BDAu ^ 42u;
    unsigned x0 = 0u + ks0;
    unsigned x1 = lo + ks1;
#define TF_R4(a,b,c,d) \
    x0 += x1; x1 = rotl32(x1,a); x1 ^= x0; \
    x0 += x1; x1 = rotl32(x1,b); x1 ^= x0; \
    x0 += x1; x1 = rotl32(x1,c); x1 ^= x0; \
    x0 += x1; x1 = rotl32(x1,d); x1 ^= x0;
    TF_R4(13,15,26,6);  x0 += ks1; x1 += ks2 + 1u;
    TF_R4(17,29,16,24); x0 += ks2; x1 += ks0 + 2u;
    TF_R4(13,15,26,6);  x0 += ks0; x1 += ks1 + 3u;
    TF_R4(17,29,16,24); x0 += ks1; x1 += ks2 + 4u;
    TF_R4(13,15,26,6);  x0 += ks2; x1 += ks0 + 5u;
#undef TF_R4
    return x0 ^ x1;
}
__device__ __forceinline__ float gumbel_g(unsigned flat) {
    unsigned bits = threefry_bits(flat);
    float u  = __uint_as_float((bits >> 9) | 0x3f800000u) - 1.0f;
    float U  = 0.001f * u;
    float t1 = U + 0.001f;
    float L1 = (float)log((double)t1);
    float A  = 0.001f - L1;
    float L2 = (float)log((double)A);
    return -L2;
}

// float -> bf16, round-to-nearest-even
__device__ __forceinline__ unsigned short f2bf(float x) {
    unsigned u = __float_as_uint(x);
    u += 0x7fffu + ((u >> 16) & 1u);
    return (unsigned short)(u >> 16);
}

// ---------------------------------------------------------------------------
// K1: blocks [0,A1BLKS): a1 = concat(x,y)@W1 + b1 (fp64) + BN partials.
//     blocks [A1BLKS, A1BLKS+CONVBLKS): convert W3 -> bf16 MFMA-B-fragment
//     layout w3s[tile][khalf][lane][8] + runtime max|W3| (atomic).
__global__ __launch_bounds__(256) void k_a1(
    const float* __restrict__ x, const float* __restrict__ y,
    const float* __restrict__ W1, const float* __restrict__ b1,
    const float* __restrict__ W3,
    float* __restrict__ a1, double* __restrict__ p1, double* __restrict__ p2,
    unsigned short* __restrict__ w3s, float* __restrict__ maxw)
{
    const int t = threadIdx.x;

    if (blockIdx.x >= A1BLKS) {
        // ---- W3 conversion: job = (tile, khalf, lane) ----
        const int job  = (blockIdx.x - A1BLKS) * 256 + t;   // 0..65535
        const int T    = job >> 7;
        const int rem  = job & 127;
        const int kh   = rem >> 6;
        const int l    = rem & 63;
        const int quad = l >> 4, col = l & 15;
        const float* src = W3 + (size_t)(kh * 32 + quad * 8) * FEATN + T * 16 + col;
        unsigned short v[8];
        float mx = 0.0f;
#pragma unroll
        for (int jj = 0; jj < 8; ++jj) {
            float xv = src[(size_t)jj * FEATN];
            mx = fmaxf(mx, fabsf(xv));
            v[jj] = f2bf(xv);
        }
        uint4 o;
        o.x = (unsigned)v[0] | ((unsigned)v[1] << 16);
        o.y = (unsigned)v[2] | ((unsigned)v[3] << 16);
        o.z = (unsigned)v[4] | ((unsigned)v[5] << 16);
        o.w = (unsigned)v[6] | ((unsigned)v[7] << 16);
        ((uint4*)w3s)[job] = o;
        // block-reduce max, one atomic per block (maxw pre-zeroed by memset)
#pragma unroll
        for (int off = 32; off; off >>= 1) mx = fmaxf(mx, __shfl_xor(mx, off));
        __shared__ float wred[4];
        if ((t & 63) == 0) wred[t >> 6] = mx;
        __syncthreads();
        if (t == 0) {
            float m = fmaxf(fmaxf(wred[0], wred[1]), fmaxf(wred[2], wred[3]));
            atomicMax((unsigned*)maxw, __float_as_uint(m));
        }
        return;
    }

    // ---- a1 branch ----
    const int j  = t;
    const int b0 = blockIdx.x * A1ROWS;
    double acc[A1ROWS];
#pragma unroll
    for (int r = 0; r < A1ROWS; ++r) acc[r] = 0.0;
    for (int i = 0; i < NZ; ++i) {
        float w = W1[i * H1 + j];
#pragma unroll
        for (int r = 0; r < A1ROWS; ++r)
            acc[r] += (double)x[(b0 + r) * NZ + i] * (double)w;
    }
#pragma unroll
    for (int i = 0; i < NC; ++i) {
        float w = W1[(NZ + i) * H1 + j];
#pragma unroll
        for (int r = 0; r < A1ROWS; ++r)
            acc[r] += (double)y[(b0 + r) * NC + i] * (double)w;
    }
    double bb = (double)b1[j];
    double s = 0.0, s2 = 0.0;
#pragma unroll
    for (int r = 0; r < A1ROWS; ++r) {
        float v = (float)(acc[r] + bb);
        a1[(b0 + r) * H1 + j] = v;
        double dv = (double)v;
        s += dv; s2 += dv * dv;
    }
    p1[blockIdx.x * H1 + j] = s;
    p2[blockIdx.x * H1 + j] = s2;
}

// ---------------------------------------------------------------------------
// Stats stage 2: reduce nprt per-block partials per column; fold gamma/beta.
__global__ __launch_bounds__(256) void k_stats2(
    const double* __restrict__ p1, const double* __restrict__ p2,
    int nprt, int ncol,
    const float* __restrict__ gamma, const float* __restrict__ beta,
    float* __restrict__ scale, float* __restrict__ shift)
{
    const int j = blockIdx.x, t = threadIdx.x;
    double s = 0.0, s2 = 0.0;
    for (int g = t; g < nprt; g += 256) {
        s  += p1[(size_t)g * ncol + j];
        s2 += p2[(size_t)g * ncol + j];
    }
#pragma unroll
    for (int off = 32; off; off >>= 1) {
        s  += __shfl_xor(s, off);
        s2 += __shfl_xor(s2, off);
    }
    __shared__ double ws1[4], ws2[4];
    if ((t & 63) == 0) { ws1[t >> 6] = s; ws2[t >> 6] = s2; }
    __syncthreads();
    if (t == 0) {
        s  = (ws1[0] + ws1[1]) + (ws1[2] + ws1[3]);
        s2 = (ws2[0] + ws2[1]) + (ws2[2] + ws2[3]);
        double mean = s * (1.0 / B_ROWS);
        double var  = s2 * (1.0 / B_ROWS) - mean * mean;
        double rstd = 1.0 / sqrt(var + 1e-5);
        double sc   = (double)gamma[j] * rstd;
        scale[j] = (float)sc;
        shift[j] = (float)((double)beta[j] - mean * sc);
    }
}

// ---------------------------------------------------------------------------
// K3: a2 = relu(bn(a1)) @ W2 + b2 (fp64 acc) + fused per-block BN partials
__global__ __launch_bounds__(256) void k_a2(
    const float* __restrict__ a1,
    const float* __restrict__ sc1, const float* __restrict__ sh1,
    const float* __restrict__ W2, const float* __restrict__ b2,
    float* __restrict__ a2, double* __restrict__ p1, double* __restrict__ p2)
{
    const int t  = threadIdx.x;
    const int k  = t & 63;
    const int rr = t >> 6;
    const int b  = blockIdx.x * 4 + rr;
    double acc = 0.0;
    for (int j = 0; j < H1; ++j) {
        float h = fmaxf(fmaf(a1[b * H1 + j], sc1[j], sh1[j]), 0.0f);
        acc += (double)h * (double)W2[j * H2 + k];
    }
    float v = (float)(acc + (double)b2[k]);
    a2[b * H2 + k] = v;

    __shared__ double ls[256], ls2[256];
    ls[t]  = (double)v;
    ls2[t] = (double)v * (double)v;
    __syncthreads();
    if (t < 64) {
        double s  = (ls[t]  + ls[t + 64])  + (ls[t + 128]  + ls[t + 192]);
        double s2 = (ls2[t] + ls2[t + 64]) + (ls2[t + 128] + ls2[t + 192]);
        p1[blockIdx.x * H2 + t] = s;
        p2[blockIdx.x * H2 + t] = s2;
    }
}

// ---------------------------------------------------------------------------
// Pass-B helpers (exact fp32 recompute, unchanged numerics from R7)
#define CHK(r, vexpr, q) { \
    float vv = (vexpr); \
    if (vv >= th) { \
        int f = fbase + q; \
        float scv = vv + gumbel_g((unsigned)(b0 + r) * (unsigned)FEATN + (unsigned)f); \
        if (scv > bS##r || (scv == bS##r && f < bI##r)) { bS##r = scv; bI##r = f; } \
    } }

#define CANDR(r) if (fineS[r][segIdx] >= thrS[r]) { \
    const float4 bbA = *(const float4*)(b3 + fbase); \
    const float4 bbB = *(const float4*)(b3 + fbase + 4); \
    float4 aA = bbA, aB = bbB; \
    const float* wrow = W3 + fbase; \
    _Pragma("unroll 2") \
    for (int j = 0; j < 64; ++j) { \
        const float4 wA = *(const float4*)(wrow); \
        const float4 wB = *(const float4*)(wrow + 4); \
        const float hr = h2T[j][r]; \
        aA.x = fmaf(hr, wA.x, aA.x); aA.y = fmaf(hr, wA.y, aA.y); \
        aA.z = fmaf(hr, wA.z, aA.z); aA.w = fmaf(hr, wA.w, aA.w); \
        aB.x = fmaf(hr, wB.x, aB.x); aB.y = fmaf(hr, wB.y, aB.y); \
        aB.z = fmaf(hr, wB.z, aB.z); aB.w = fmaf(hr, wB.w, aB.w); \
        wrow += FEATN; \
    } \
    const float th = thrS[r]; \
    CHK(r, aA.x, 0) CHK(r, aA.y, 1) CHK(r, aA.z, 2) CHK(r, aA.w, 3) \
    CHK(r, aB.x, 4) CHK(r, aB.y, 5) CHK(r, aB.z, 6) CHK(r, aB.w, 7) }

#define REDROW(r) { \
    float v = bS##r; int ix = bI##r; \
    _Pragma("unroll") \
    for (int off = 32; off; off >>= 1) { \
        float ov = __shfl_xor(v, off); \
        int   oi = __shfl_xor(ix, off); \
        if (ov > v || (ov == v && oi < ix)) { v = ov; ix = oi; } \
    } \
    if (lane == 0) { redS[r][wv] = v; redI[r][wv] = ix; } }

// K5: pass A via bf16 MFMA (bounds only, per-row error-margin); pass B exact
// fp32 on qualifying (row, 128-f segment) cells; gather codebook row.
__global__ __launch_bounds__(512)
__attribute__((amdgpu_waves_per_eu(4, 4)))
void k_main(
    const float* __restrict__ a2,
    const float* __restrict__ sc2, const float* __restrict__ sh2,
    const float* __restrict__ W3, const float* __restrict__ b3,
    const unsigned short* __restrict__ w3s, const float* __restrict__ maxw,
    const float* __restrict__ codebook, float* __restrict__ out)
{
    const int t    = threadIdx.x;
    const int wv   = t >> 6;           // wave 0..7
    const int lane = t & 63;
    const int quad = lane >> 4, col = lane & 15;
    const int b0   = blockIdx.x * RROWS;

    __shared__ __align__(16) float h2T[64][RROWS];  // [j][r] fp32, 4 KB
    __shared__ float fineS[RROWS][64];              // per-(row, 128-f seg) max
    __shared__ float thrS[RROWS];
    __shared__ float redS[RROWS][8];
    __shared__ int   redI[RROWS][8];
    __shared__ int   rowInd[RROWS];
    __shared__ float maxwS;

    if (t == 0) maxwS = maxw[0];
    // h2 = relu(bn(a2)) for our 16 rows
    for (int q = t; q < RROWS * 64; q += 512) {
        int j = q >> 4, r = q & 15;
        float v = a2[(b0 + r) * H2 + j];
        h2T[j][r] = fmaxf(fmaf(v, sc2[j], sh2[j]), 0.0f);
    }
    __syncthreads();

    // Build A fragments (bf16): A[m=col][k=quad*8+jj], khalf 0/1
    short8 aF0, aF1;
#pragma unroll
    for (int jj = 0; jj < 8; ++jj) {
        aF0[jj] = (short)f2bf(h2T[quad * 8 + jj][col]);
        aF1[jj] = (short)f2bf(h2T[32 + quad * 8 + jj][col]);
    }

    // ---- Pass A: MFMA sweep. Wave wv owns tiles [wv*64, wv*64+64) ----
    {
        const uint4* wp = (const uint4*)w3s + (size_t)wv * 8192 + lane;
        for (int s = 0; s < 8; ++s) {           // 8 segs of 8 tiles (128 f)
            float rm0 = -1e30f, rm1 = -1e30f, rm2 = -1e30f, rm3 = -1e30f;
#pragma unroll
            for (int u = 0; u < 8; ++u) {
                const int T = wv * 64 + s * 8 + u;
                uint4 bw0 = wp[0];
                uint4 bw1 = wp[64];
                wp += 128;
                float b3f = b3[T * 16 + col];
                f32x4 acc = {b3f, b3f, b3f, b3f};   // C init = b3 (D = A.B + C)
                acc = __builtin_amdgcn_mfma_f32_16x16x32_bf16(
                          aF0, *(const short8*)&bw0, acc, 0, 0, 0);
                acc = __builtin_amdgcn_mfma_f32_16x16x32_bf16(
                          aF1, *(const short8*)&bw1, acc, 0, 0, 0);
                rm0 = fmaxf(rm0, acc[0]); rm1 = fmaxf(rm1, acc[1]);
                rm2 = fmaxf(rm2, acc[2]); rm3 = fmaxf(rm3, acc[3]);
            }
            // reduce over 16 cols (lanes sharing quad)
#pragma unroll
            for (int off = 1; off < 16; off <<= 1) {
                rm0 = fmaxf(rm0, __shfl_xor(rm0, off));
                rm1 = fmaxf(rm1, __shfl_xor(rm1, off));
                rm2 = fmaxf(rm2, __shfl_xor(rm2, off));
                rm3 = fmaxf(rm3, __shfl_xor(rm3, off));
            }
            if (col == 0) {
                const int seg = wv * 8 + s;
                fineS[quad * 4 + 0][seg] = rm0;
                fineS[quad * 4 + 1][seg] = rm1;
                fineS[quad * 4 + 2][seg] = rm2;
                fineS[quad * 4 + 3][seg] = rm3;
            }
        }
    }
    __syncthreads();

    // ---- Per-row threshold with rigorous bf16 error margin ----
    if (t < RROWS) {
        float S = 0.0f;
        for (int j = 0; j < 64; ++j) S += fabsf(h2T[j][t]);
        float gm = -1e30f;
        for (int s = 0; s < 64; ++s) gm = fmaxf(gm, fineS[t][s]);
        float e = S * maxwS * (1.0f / 256.0f);   // |Δlogit| <= S*maxW*2^-8
        thrS[t] = gm - (0.1068f + e + 1e-3f);
    }
    __syncthreads();

    // ---- Pass B: exact fp32 on qualifying (row, seg) cells ----
    float bS0=-1e30f,bS1=-1e30f,bS2=-1e30f,bS3=-1e30f,bS4=-1e30f,bS5=-1e30f,
          bS6=-1e30f,bS7=-1e30f,bS8=-1e30f,bS9=-1e30f,bS10=-1e30f,bS11=-1e30f,
          bS12=-1e30f,bS13=-1e30f,bS14=-1e30f,bS15=-1e30f;
    int bI0=0,bI1=0,bI2=0,bI3=0,bI4=0,bI5=0,bI6=0,bI7=0,
        bI8=0,bI9=0,bI10=0,bI11=0,bI12=0,bI13=0,bI14=0,bI15=0;

    for (int fc = 0; fc < 2; ++fc) {
        const int fbase  = fc * 4096 + t * 8;
        const int segIdx = fbase >> 7;
        CANDR(0)  CANDR(1)  CANDR(2)  CANDR(3)
        CANDR(4)  CANDR(5)  CANDR(6)  CANDR(7)
        CANDR(8)  CANDR(9)  CANDR(10) CANDR(11)
        CANDR(12) CANDR(13) CANDR(14) CANDR(15)
    }

    REDROW(0)  REDROW(1)  REDROW(2)  REDROW(3)
    REDROW(4)  REDROW(5)  REDROW(6)  REDROW(7)
    REDROW(8)  REDROW(9)  REDROW(10) REDROW(11)
    REDROW(12) REDROW(13) REDROW(14) REDROW(15)
    __syncthreads();
    if (t < RROWS) {
        float v = -1e30f; int ix = 0;
        for (int w = 0; w < 8; ++w) {
            float ov = redS[t][w]; int oi = redI[t][w];
            if (ov > v || (ov == v && oi < ix && ov > -1e29f)) { v = ov; ix = oi; }
        }
        rowInd[t] = ix & (FEATN - 1);
    }
    __syncthreads();

    // out[b,:] = codebook[ind,:] — 2 rows in parallel (512 thr, 256 f4/row)
    {
        const int rr = t >> 8, tt = t & 255;
        for (int rp = 0; rp < RROWS / 2; ++rp) {
            const int r = rp * 2 + rr;
            const int ind = rowInd[r];
            const float4* src = (const float4*)(codebook + (size_t)ind * FDIM);
            float4*       dst = (float4*)(out + (size_t)(b0 + r) * FDIM);
            dst[tt] = src[tt];
        }
    }
}

// ---------------------------------------------------------------------------
extern "C" void kernel_launch(void* const* d_in, const int* in_sizes, int n_in,
                              void* d_out, int out_size, void* d_ws, size_t ws_size,
                              hipStream_t stream)
{
    const float* x   = (const float*)d_in[0];
    const float* y   = (const float*)d_in[1];
    const float* W1  = (const float*)d_in[2];
    const float* b1  = (const float*)d_in[3];
    const float* g1  = (const float*)d_in[4];
    const float* be1 = (const float*)d_in[5];
    const float* W2  = (const float*)d_in[6];
    const float* b2  = (const float*)d_in[7];
    const float* g2  = (const float*)d_in[8];
    const float* be2 = (const float*)d_in[9];
    const float* W3  = (const float*)d_in[10];
    const float* b3  = (const float*)d_in[11];
    const float* cb  = (const float*)d_in[12];
    float* out = (float*)d_out;

    float* ws  = (float*)d_ws;
    float* a1  = ws;                          // 2097152 f32 (8 MB)
    float* a2  = a1 + B_ROWS * H1;            // 524288 f32 (2 MB)
    float* sc1 = a2 + B_ROWS * H2;
    float* sh1 = sc1 + H1;
    float* sc2 = sh1 + H1;
    float* sh2 = sc2 + H2;
    double* p1 = (double*)(sh2 + H2);         // 131072 f64 (1 MB)
    double* p2 = p1 + A2BLKS * H2;            // 131072 f64 (1 MB)
    unsigned short* w3s = (unsigned short*)(p2 + A2BLKS * H2);  // 1 MB bf16
    float* maxw = (float*)(w3s + NTILE * 2 * 64 * 8);           // 1 f32
    // total ws ≈ 13.0 MB

    hipMemsetAsync(maxw, 0, 4, stream);
    k_a1    <<<A1BLKS + CONVBLKS, 256, 0, stream>>>(x, y, W1, b1, W3,
                                                    a1, p1, p2, w3s, maxw);
    k_stats2<<<H1, 256, 0, stream>>>(p1, p2, A1BLKS, H1, g1, be1, sc1, sh1);
    k_a2    <<<A2BLKS, 256, 0, stream>>>(a1, sc1, sh1, W2, b2, a2, p1, p2);
    k_stats2<<<H2, 256, 0, stream>>>(p1, p2, A2BLKS, H2, g2, be2, sc2, sh2);
    k_main  <<<B_ROWS / RROWS, 512, 0, stream>>>(a2, sc2, sh2, W3, b3,
                                                 w3s, maxw, cb, out);
}

// Round 9
// 304.493 us; speedup vs baseline: 7.4828x; 1.3801x over previous
//
#include <hip/hip_runtime.h>
#include <math.h>

// ---------------------------------------------------------------------------
#define B_ROWS   8192
#define NZ       100
#define NC       2
#define H1       256
#define H2       64
#define FEATN    8192
#define FDIM     1024
#define RROWS    16            // rows per k_main block = MFMA M
#define NTILE    (FEATN / 16)  // 512 16-col MFMA tiles
#define A1ROWS   16
#define A1BLKS   (B_ROWS / A1ROWS)   // 512
#define CONVBLKS 256                 // w3 conversion blocks fused into k_a1
#define A2BLKS   (B_ROWS / 4)        // 2048

typedef __attribute__((ext_vector_type(8))) short short8;
typedef __attribute__((ext_vector_type(4))) float f32x4;

// ---------------------------------------------------------------------------
// JAX threefry2x32, partitionable, key=(0,42), counter=(0, flat)
__device__ __forceinline__ unsigned rotl32(unsigned v, int r) {
    return (v << r) | (v >> (32 - r));
}
__device__ __forceinline__ unsigned threefry_bits(unsigned lo) {
    const unsigned ks0 = 0u, ks1 = 42u, ks2 = 0x1BD11BDAu ^ 42u;
    unsigned x0 = 0u + ks0;
    unsigned x1 = lo + ks1;
#define TF_R4(a,b,c,d) \
    x0 += x1; x1 = rotl32(x1,a); x1 ^= x0; \
    x0 += x1; x1 = rotl32(x1,b); x1 ^= x0; \
    x0 += x1; x1 = rotl32(x1,c); x1 ^= x0; \
    x0 += x1; x1 = rotl32(x1,d); x1 ^= x0;
    TF_R4(13,15,26,6);  x0 += ks1; x1 += ks2 + 1u;
    TF_R4(17,29,16,24); x0 += ks2; x1 += ks0 + 2u;
    TF_R4(13,15,26,6);  x0 += ks0; x1 += ks1 + 3u;
    TF_R4(17,29,16,24); x0 += ks1; x1 += ks2 + 4u;
    TF_R4(13,15,26,6);  x0 += ks2; x1 += ks0 + 5u;
#undef TF_R4
    return x0 ^ x1;
}
__device__ __forceinline__ float gumbel_g(unsigned flat) {
    unsigned bits = threefry_bits(flat);
    float u  = __uint_as_float((bits >> 9) | 0x3f800000u) - 1.0f;
    float U  = 0.001f * u;
    float t1 = U + 0.001f;
    float L1 = (float)log((double)t1);
    float A  = 0.001f - L1;
    float L2 = (float)log((double)A);
    return -L2;
}

// float -> bf16 RNE
__device__ __forceinline__ unsigned short f2bf(float x) {
    unsigned u = __float_as_uint(x);
    u += 0x7fffu + ((u >> 16) & 1u);
    return (unsigned short)(u >> 16);
}
// order-preserving float -> u32
__device__ __forceinline__ unsigned fmono(float x) {
    unsigned b = __float_as_uint(x);
    return (b & 0x80000000u) ? ~b : (b | 0x80000000u);
}

// ---------------------------------------------------------------------------
// K1: blocks [0,A1BLKS): a1 = concat(x,y)@W1 + b1 (fp64) + BN partials.
//     blocks [A1BLKS,..): convert W3 -> bf16 MFMA-B-fragment layout + max|W3|.
__global__ __launch_bounds__(256) void k_a1(
    const float* __restrict__ x, const float* __restrict__ y,
    const float* __restrict__ W1, const float* __restrict__ b1,
    const float* __restrict__ W3,
    float* __restrict__ a1, double* __restrict__ p1, double* __restrict__ p2,
    unsigned short* __restrict__ w3s, float* __restrict__ maxw)
{
    const int t = threadIdx.x;

    if (blockIdx.x >= A1BLKS) {
        const int job  = (blockIdx.x - A1BLKS) * 256 + t;   // 0..65535
        const int T    = job >> 7;
        const int rem  = job & 127;
        const int kh   = rem >> 6;
        const int l    = rem & 63;
        const int quad = l >> 4, col = l & 15;
        const float* src = W3 + (size_t)(kh * 32 + quad * 8) * FEATN + T * 16 + col;
        unsigned short v[8];
        float mx = 0.0f;
#pragma unroll
        for (int jj = 0; jj < 8; ++jj) {
            float xv = src[(size_t)jj * FEATN];
            mx = fmaxf(mx, fabsf(xv));
            v[jj] = f2bf(xv);
        }
        uint4 o;
        o.x = (unsigned)v[0] | ((unsigned)v[1] << 16);
        o.y = (unsigned)v[2] | ((unsigned)v[3] << 16);
        o.z = (unsigned)v[4] | ((unsigned)v[5] << 16);
        o.w = (unsigned)v[6] | ((unsigned)v[7] << 16);
        ((uint4*)w3s)[job] = o;
#pragma unroll
        for (int off = 32; off; off >>= 1) mx = fmaxf(mx, __shfl_xor(mx, off));
        __shared__ float wred[4];
        if ((t & 63) == 0) wred[t >> 6] = mx;
        __syncthreads();
        if (t == 0) {
            float m = fmaxf(fmaxf(wred[0], wred[1]), fmaxf(wred[2], wred[3]));
            atomicMax((unsigned*)maxw, __float_as_uint(m));
        }
        return;
    }

    const int j  = t;
    const int b0 = blockIdx.x * A1ROWS;
    double acc[A1ROWS];
#pragma unroll
    for (int r = 0; r < A1ROWS; ++r) acc[r] = 0.0;
    for (int i = 0; i < NZ; ++i) {
        float w = W1[i * H1 + j];
#pragma unroll
        for (int r = 0; r < A1ROWS; ++r)
            acc[r] += (double)x[(b0 + r) * NZ + i] * (double)w;
    }
#pragma unroll
    for (int i = 0; i < NC; ++i) {
        float w = W1[(NZ + i) * H1 + j];
#pragma unroll
        for (int r = 0; r < A1ROWS; ++r)
            acc[r] += (double)y[(b0 + r) * NC + i] * (double)w;
    }
    double bb = (double)b1[j];
    double s = 0.0, s2 = 0.0;
#pragma unroll
    for (int r = 0; r < A1ROWS; ++r) {
        float v = (float)(acc[r] + bb);
        a1[(b0 + r) * H1 + j] = v;
        double dv = (double)v;
        s += dv; s2 += dv * dv;
    }
    p1[blockIdx.x * H1 + j] = s;
    p2[blockIdx.x * H1 + j] = s2;
}

// ---------------------------------------------------------------------------
__global__ __launch_bounds__(256) void k_stats2(
    const double* __restrict__ p1, const double* __restrict__ p2,
    int nprt, int ncol,
    const float* __restrict__ gamma, const float* __restrict__ beta,
    float* __restrict__ scale, float* __restrict__ shift)
{
    const int j = blockIdx.x, t = threadIdx.x;
    double s = 0.0, s2 = 0.0;
    for (int g = t; g < nprt; g += 256) {
        s  += p1[(size_t)g * ncol + j];
        s2 += p2[(size_t)g * ncol + j];
    }
#pragma unroll
    for (int off = 32; off; off >>= 1) {
        s  += __shfl_xor(s, off);
        s2 += __shfl_xor(s2, off);
    }
    __shared__ double ws1[4], ws2[4];
    if ((t & 63) == 0) { ws1[t >> 6] = s; ws2[t >> 6] = s2; }
    __syncthreads();
    if (t == 0) {
        s  = (ws1[0] + ws1[1]) + (ws1[2] + ws1[3]);
        s2 = (ws2[0] + ws2[1]) + (ws2[2] + ws2[3]);
        double mean = s * (1.0 / B_ROWS);
        double var  = s2 * (1.0 / B_ROWS) - mean * mean;
        double rstd = 1.0 / sqrt(var + 1e-5);
        double sc   = (double)gamma[j] * rstd;
        scale[j] = (float)sc;
        shift[j] = (float)((double)beta[j] - mean * sc);
    }
}

// ---------------------------------------------------------------------------
__global__ __launch_bounds__(256) void k_a2(
    const float* __restrict__ a1,
    const float* __restrict__ sc1, const float* __restrict__ sh1,
    const float* __restrict__ W2, const float* __restrict__ b2,
    float* __restrict__ a2, double* __restrict__ p1, double* __restrict__ p2)
{
    const int t  = threadIdx.x;
    const int k  = t & 63;
    const int rr = t >> 6;
    const int b  = blockIdx.x * 4 + rr;
    double acc = 0.0;
    for (int j = 0; j < H1; ++j) {
        float h = fmaxf(fmaf(a1[b * H1 + j], sc1[j], sh1[j]), 0.0f);
        acc += (double)h * (double)W2[j * H2 + k];
    }
    float v = (float)(acc + (double)b2[k]);
    a2[b * H2 + k] = v;

    __shared__ double ls[256], ls2[256];
    ls[t]  = (double)v;
    ls2[t] = (double)v * (double)v;
    __syncthreads();
    if (t < 64) {
        double s  = (ls[t]  + ls[t + 64])  + (ls[t + 128]  + ls[t + 192]);
        double s2 = (ls2[t] + ls2[t + 64]) + (ls2[t + 128] + ls2[t + 192]);
        p1[blockIdx.x * H2 + t] = s;
        p2[blockIdx.x * H2 + t] = s2;
    }
}

// ---------------------------------------------------------------------------
// K5: pass A = bf16 MFMA bounds (prefetched); worklist of qualifying
// (row, 128-f-seg) cells; pass B = ONE shared fp32 recompute loop over the
// worklist (no code duplication — R8's 32 unrolled copies thrashed I-cache);
// winner via packed u64 LDS atomicMax; gather codebook row.
__global__ __launch_bounds__(512)
__attribute__((amdgpu_waves_per_eu(4, 4)))
void k_main(
    const float* __restrict__ a2,
    const float* __restrict__ sc2, const float* __restrict__ sh2,
    const float* __restrict__ W3, const float* __restrict__ b3,
    const unsigned short* __restrict__ w3s, const float* __restrict__ maxw,
    const float* __restrict__ codebook, float* __restrict__ out)
{
    const int t    = threadIdx.x;
    const int wv   = t >> 6;           // wave 0..7
    const int lane = t & 63;
    const int quad = lane >> 4, col = lane & 15;
    const int b0   = blockIdx.x * RROWS;

    __shared__ __align__(16) float h2T[64][RROWS];  // [j][r], 4 KB
    __shared__ float fineS[RROWS][64];              // per-(row, 128-f seg) max
    __shared__ float thrS[RROWS];
    __shared__ unsigned long long best[RROWS];
    __shared__ unsigned short wl[1024];             // worklist (worst-case all)
    __shared__ int wlN;
    __shared__ int rowInd[RROWS];
    __shared__ float maxwS;

    if (t == 0) { maxwS = maxw[0]; wlN = 0; }
    for (int q = t; q < RROWS * 64; q += 512) {
        int j = q >> 4, r = q & 15;
        float v = a2[(b0 + r) * H2 + j];
        h2T[j][r] = fmaxf(fmaf(v, sc2[j], sh2[j]), 0.0f);
    }
    __syncthreads();

    // A fragments (bf16): A[m=col][k=quad*8+jj], k-halves 0/1
    short8 aF0, aF1;
#pragma unroll
    for (int jj = 0; jj < 8; ++jj) {
        aF0[jj] = (short)f2bf(h2T[quad * 8 + jj][col]);
        aF1[jj] = (short)f2bf(h2T[32 + quad * 8 + jj][col]);
    }

    // ---- Pass A: MFMA sweep with next-tile prefetch ----
    {
        const uint4* wp  = (const uint4*)w3s + (size_t)wv * 8192 + lane;
        const float* b3p = b3 + wv * 1024 + col;
        uint4 c0 = wp[0], c1 = wp[64];
        float bc = b3p[0];
        for (int s = 0; s < 8; ++s) {
            float rm0 = -1e30f, rm1 = -1e30f, rm2 = -1e30f, rm3 = -1e30f;
#pragma unroll
            for (int u = 0; u < 8; ++u) {
                const int idx = s * 8 + u;
                // prefetch next tile (clamped on the final tile: no OOB)
                const uint4* qn = (idx < 63) ? wp + 128 : wp;
                const float* bn = (idx < 63) ? b3p + 16 : b3p;
                uint4 n0 = qn[0], n1 = qn[64];
                float nb = bn[0];
                f32x4 acc = {bc, bc, bc, bc};
                acc = __builtin_amdgcn_mfma_f32_16x16x32_bf16(
                          aF0, *(const short8*)&c0, acc, 0, 0, 0);
                acc = __builtin_amdgcn_mfma_f32_16x16x32_bf16(
                          aF1, *(const short8*)&c1, acc, 0, 0, 0);
                rm0 = fmaxf(rm0, acc[0]); rm1 = fmaxf(rm1, acc[1]);
                rm2 = fmaxf(rm2, acc[2]); rm3 = fmaxf(rm3, acc[3]);
                c0 = n0; c1 = n1; bc = nb;
                wp += 128; b3p += 16;
            }
#pragma unroll
            for (int off = 1; off < 16; off <<= 1) {
                rm0 = fmaxf(rm0, __shfl_xor(rm0, off));
                rm1 = fmaxf(rm1, __shfl_xor(rm1, off));
                rm2 = fmaxf(rm2, __shfl_xor(rm2, off));
                rm3 = fmaxf(rm3, __shfl_xor(rm3, off));
            }
            if (col == 0) {
                const int seg = wv * 8 + s;
                fineS[quad * 4 + 0][seg] = rm0;
                fineS[quad * 4 + 1][seg] = rm1;
                fineS[quad * 4 + 2][seg] = rm2;
                fineS[quad * 4 + 3][seg] = rm3;
            }
        }
    }
    __syncthreads();

    // ---- Thresholds (rigorous bf16 margin) + init best ----
    if (t < RROWS) {
        float S = 0.0f;
        for (int j = 0; j < 64; ++j) S += fabsf(h2T[j][t]);
        float gm = -1e30f;
        for (int s = 0; s < 64; ++s) gm = fmaxf(gm, fineS[t][s]);
        float e = S * maxwS * (1.0f / 256.0f);   // |Δlogit| <= S*maxW*2^-8
        thrS[t] = gm - (0.1068f + e + 1e-3f);
        best[t] = 0ull;
    }
    __syncthreads();

    // ---- Build worklist of qualifying (row, seg) cells ----
    for (int c = t; c < RROWS * 64; c += 512) {
        int r = c >> 6, seg = c & 63;
        if (fineS[r][seg] >= thrS[r]) {
            int k = atomicAdd(&wlN, 1);
            wl[k] = (unsigned short)((r << 6) | seg);
        }
    }
    __syncthreads();

    // ---- Pass B: one shared loop; wave per cell; lane per 2 f ----
    const int n = wlN;
    for (int i = wv; i < n; i += 8) {
        const int e   = wl[i];
        const int r   = e >> 6;
        const int seg = e & 63;
        const int f0  = seg * 128 + lane;       // and f0+64
        float acc0 = b3[f0], acc1 = b3[f0 + 64];
        const float* wcol = W3 + f0;
#pragma unroll 4
        for (int j = 0; j < 64; ++j) {
            const float h  = h2T[j][r];         // LDS broadcast
            acc0 = fmaf(h, wcol[0],  acc0);     // coalesced 256 B
            acc1 = fmaf(h, wcol[64], acc1);
            wcol += FEATN;
        }
        const float th = thrS[r];
        if (acc0 >= th) {
            float sc = acc0 + gumbel_g((unsigned)(b0 + r) * (unsigned)FEATN + (unsigned)f0);
            unsigned long long pk = ((unsigned long long)fmono(sc) << 32)
                                  | (unsigned)(FEATN - 1 - f0);
            atomicMax(&best[r], pk);
        }
        if (acc1 >= th) {
            int f1 = f0 + 64;
            float sc = acc1 + gumbel_g((unsigned)(b0 + r) * (unsigned)FEATN + (unsigned)f1);
            unsigned long long pk = ((unsigned long long)fmono(sc) << 32)
                                  | (unsigned)(FEATN - 1 - f1);
            atomicMax(&best[r], pk);
        }
    }
    __syncthreads();
    if (t < RROWS) {
        rowInd[t] = (FEATN - 1 - (int)(best[t] & 0xFFFFFFFFull)) & (FEATN - 1);
    }
    __syncthreads();

    // ---- out[b,:] = codebook[ind,:] ----
    {
        const int rr = t >> 8, tt = t & 255;
        for (int rp = 0; rp < RROWS / 2; ++rp) {
            const int r = rp * 2 + rr;
            const int ind = rowInd[r];
            const float4* src = (const float4*)(codebook + (size_t)ind * FDIM);
            float4*       dst = (float4*)(out + (size_t)(b0 + r) * FDIM);
            dst[tt] = src[tt];
        }
    }
}

// ---------------------------------------------------------------------------
extern "C" void kernel_launch(void* const* d_in, const int* in_sizes, int n_in,
                              void* d_out, int out_size, void* d_ws, size_t ws_size,
                              hipStream_t stream)
{
    const float* x   = (const float*)d_in[0];
    const float* y   = (const float*)d_in[1];
    const float* W1  = (const float*)d_in[2];
    const float* b1  = (const float*)d_in[3];
    const float* g1  = (const float*)d_in[4];
    const float* be1 = (const float*)d_in[5];
    const float* W2  = (const float*)d_in[6];
    const float* b2  = (const float*)d_in[7];
    const float* g2  = (const float*)d_in[8];
    const float* be2 = (const float*)d_in[9];
    const float* W3  = (const float*)d_in[10];
    const float* b3  = (const float*)d_in[11];
    const float* cb  = (const float*)d_in[12];
    float* out = (float*)d_out;

    float* ws  = (float*)d_ws;
    float* a1  = ws;                          // 8 MB
    float* a2  = a1 + B_ROWS * H1;            // 2 MB
    float* sc1 = a2 + B_ROWS * H2;
    float* sh1 = sc1 + H1;
    float* sc2 = sh1 + H1;
    float* sh2 = sc2 + H2;
    double* p1 = (double*)(sh2 + H2);         // 1 MB
    double* p2 = p1 + A2BLKS * H2;            // 1 MB
    unsigned short* w3s = (unsigned short*)(p2 + A2BLKS * H2);  // 1 MB bf16
    float* maxw = (float*)(w3s + NTILE * 2 * 64 * 8);           // 1 f32

    hipMemsetAsync(maxw, 0, 4, stream);
    k_a1    <<<A1BLKS + CONVBLKS, 256, 0, stream>>>(x, y, W1, b1, W3,
                                                    a1, p1, p2, w3s, maxw);
    k_stats2<<<H1, 256, 0, stream>>>(p1, p2, A1BLKS, H1, g1, be1, sc1, sh1);
    k_a2    <<<A2BLKS, 256, 0, stream>>>(a1, sc1, sh1, W2, b2, a2, p1, p2);
    k_stats2<<<H2, 256, 0, stream>>>(p1, p2, A2BLKS, H2, g2, be2, sc2, sh2);
    k_main  <<<B_ROWS / RROWS, 512, 0, stream>>>(a2, sc2, sh2, W3, b3,
                                                 w3s, maxw, cb, out);
}

// Round 11
// 304.467 us; speedup vs baseline: 7.4835x; 1.0001x over previous
//
#include <hip/hip_runtime.h>
#include <math.h>

// ---------------------------------------------------------------------------
#define B_ROWS   8192
#define NZ       100
#define NC       2
#define H1       256
#define H2       64
#define FEATN    8192
#define FDIM     1024
#define RROWS    16            // rows per k_main block = MFMA M
#define NTILE    (FEATN / 16)  // 512 16-col MFMA tiles
#define A1ROWS   16
#define A1BLKS   (B_ROWS / A1ROWS)   // 512
#define CONVBLKS 256                 // w3 conversion blocks fused into k_a1
#define A2BLKS   (B_ROWS / 4)        // 2048

typedef __attribute__((ext_vector_type(8))) short short8;
typedef __attribute__((ext_vector_type(4))) float f32x4;

// ---------------------------------------------------------------------------
// JAX threefry2x32, partitionable, key=(0,42), counter=(0, flat)
__device__ __forceinline__ unsigned rotl32(unsigned v, int r) {
    return (v << r) | (v >> (32 - r));
}
__device__ __forceinline__ unsigned threefry_bits(unsigned lo) {
    const unsigned ks0 = 0u, ks1 = 42u, ks2 = 0x1BD11BDAu ^ 42u;
    unsigned x0 = 0u + ks0;
    unsigned x1 = lo + ks1;
#define TF_R4(a,b,c,d) \
    x0 += x1; x1 = rotl32(x1,a); x1 ^= x0; \
    x0 += x1; x1 = rotl32(x1,b); x1 ^= x0; \
    x0 += x1; x1 = rotl32(x1,c); x1 ^= x0; \
    x0 += x1; x1 = rotl32(x1,d); x1 ^= x0;
    TF_R4(13,15,26,6);  x0 += ks1; x1 += ks2 + 1u;
    TF_R4(17,29,16,24); x0 += ks2; x1 += ks0 + 2u;
    TF_R4(13,15,26,6);  x0 += ks0; x1 += ks1 + 3u;
    TF_R4(17,29,16,24); x0 += ks1; x1 += ks2 + 4u;
    TF_R4(13,15,26,6);  x0 += ks2; x1 += ks0 + 5u;
#undef TF_R4
    return x0 ^ x1;
}
__device__ __forceinline__ float gumbel_g(unsigned flat) {
    unsigned bits = threefry_bits(flat);
    float u  = __uint_as_float((bits >> 9) | 0x3f800000u) - 1.0f;
    float U  = 0.001f * u;
    float t1 = U + 0.001f;
    float L1 = (float)log((double)t1);
    float A  = 0.001f - L1;
    float L2 = (float)log((double)A);
    return -L2;
}

// float -> bf16 RNE
__device__ __forceinline__ unsigned short f2bf(float x) {
    unsigned u = __float_as_uint(x);
    u += 0x7fffu + ((u >> 16) & 1u);
    return (unsigned short)(u >> 16);
}
// order-preserving float -> u32
__device__ __forceinline__ unsigned fmono(float x) {
    unsigned b = __float_as_uint(x);
    return (b & 0x80000000u) ? ~b : (b | 0x80000000u);
}

// ---------------------------------------------------------------------------
// K1: blocks [0,A1BLKS): a1 = concat(x,y)@W1 + b1 (fp64) + BN partials.
//     blocks [A1BLKS,..): convert W3 -> bf16 MFMA-B-fragment layout + max|W3|.
__global__ __launch_bounds__(256) void k_a1(
    const float* __restrict__ x, const float* __restrict__ y,
    const float* __restrict__ W1, const float* __restrict__ b1,
    const float* __restrict__ W3,
    float* __restrict__ a1, double* __restrict__ p1, double* __restrict__ p2,
    unsigned short* __restrict__ w3s, float* __restrict__ maxw)
{
    const int t = threadIdx.x;

    if (blockIdx.x >= A1BLKS) {
        const int job  = (blockIdx.x - A1BLKS) * 256 + t;   // 0..65535
        const int T    = job >> 7;
        const int rem  = job & 127;
        const int kh   = rem >> 6;
        const int l    = rem & 63;
        const int quad = l >> 4, col = l & 15;
        const float* src = W3 + (size_t)(kh * 32 + quad * 8) * FEATN + T * 16 + col;
        unsigned short v[8];
        float mx = 0.0f;
#pragma unroll
        for (int jj = 0; jj < 8; ++jj) {
            float xv = src[(size_t)jj * FEATN];
            mx = fmaxf(mx, fabsf(xv));
            v[jj] = f2bf(xv);
        }
        uint4 o;
        o.x = (unsigned)v[0] | ((unsigned)v[1] << 16);
        o.y = (unsigned)v[2] | ((unsigned)v[3] << 16);
        o.z = (unsigned)v[4] | ((unsigned)v[5] << 16);
        o.w = (unsigned)v[6] | ((unsigned)v[7] << 16);
        ((uint4*)w3s)[job] = o;
#pragma unroll
        for (int off = 32; off; off >>= 1) mx = fmaxf(mx, __shfl_xor(mx, off));
        __shared__ float wred[4];
        if ((t & 63) == 0) wred[t >> 6] = mx;
        __syncthreads();
        if (t == 0) {
            float m = fmaxf(fmaxf(wred[0], wred[1]), fmaxf(wred[2], wred[3]));
            atomicMax((unsigned*)maxw, __float_as_uint(m));
        }
        return;
    }

    const int j  = t;
    const int b0 = blockIdx.x * A1ROWS;
    double acc[A1ROWS];
#pragma unroll
    for (int r = 0; r < A1ROWS; ++r) acc[r] = 0.0;
    for (int i = 0; i < NZ; ++i) {
        float w = W1[i * H1 + j];
#pragma unroll
        for (int r = 0; r < A1ROWS; ++r)
            acc[r] += (double)x[(b0 + r) * NZ + i] * (double)w;
    }
#pragma unroll
    for (int i = 0; i < NC; ++i) {
        float w = W1[(NZ + i) * H1 + j];
#pragma unroll
        for (int r = 0; r < A1ROWS; ++r)
            acc[r] += (double)y[(b0 + r) * NC + i] * (double)w;
    }
    double bb = (double)b1[j];
    double s = 0.0, s2 = 0.0;
#pragma unroll
    for (int r = 0; r < A1ROWS; ++r) {
        float v = (float)(acc[r] + bb);
        a1[(b0 + r) * H1 + j] = v;
        double dv = (double)v;
        s += dv; s2 += dv * dv;
    }
    p1[blockIdx.x * H1 + j] = s;
    p2[blockIdx.x * H1 + j] = s2;
}

// ---------------------------------------------------------------------------
__global__ __launch_bounds__(256) void k_stats2(
    const double* __restrict__ p1, const double* __restrict__ p2,
    int nprt, int ncol,
    const float* __restrict__ gamma, const float* __restrict__ beta,
    float* __restrict__ scale, float* __restrict__ shift)
{
    const int j = blockIdx.x, t = threadIdx.x;
    double s = 0.0, s2 = 0.0;
    for (int g = t; g < nprt; g += 256) {
        s  += p1[(size_t)g * ncol + j];
        s2 += p2[(size_t)g * ncol + j];
    }
#pragma unroll
    for (int off = 32; off; off >>= 1) {
        s  += __shfl_xor(s, off);
        s2 += __shfl_xor(s2, off);
    }
    __shared__ double ws1[4], ws2[4];
    if ((t & 63) == 0) { ws1[t >> 6] = s; ws2[t >> 6] = s2; }
    __syncthreads();
    if (t == 0) {
        s  = (ws1[0] + ws1[1]) + (ws1[2] + ws1[3]);
        s2 = (ws2[0] + ws2[1]) + (ws2[2] + ws2[3]);
        double mean = s * (1.0 / B_ROWS);
        double var  = s2 * (1.0 / B_ROWS) - mean * mean;
        double rstd = 1.0 / sqrt(var + 1e-5);
        double sc   = (double)gamma[j] * rstd;
        scale[j] = (float)sc;
        shift[j] = (float)((double)beta[j] - mean * sc);
    }
}

// ---------------------------------------------------------------------------
__global__ __launch_bounds__(256) void k_a2(
    const float* __restrict__ a1,
    const float* __restrict__ sc1, const float* __restrict__ sh1,
    const float* __restrict__ W2, const float* __restrict__ b2,
    float* __restrict__ a2, double* __restrict__ p1, double* __restrict__ p2)
{
    const int t  = threadIdx.x;
    const int k  = t & 63;
    const int rr = t >> 6;
    const int b  = blockIdx.x * 4 + rr;
    double acc = 0.0;
    for (int j = 0; j < H1; ++j) {
        float h = fmaxf(fmaf(a1[b * H1 + j], sc1[j], sh1[j]), 0.0f);
        acc += (double)h * (double)W2[j * H2 + k];
    }
    float v = (float)(acc + (double)b2[k]);
    a2[b * H2 + k] = v;

    __shared__ double ls[256], ls2[256];
    ls[t]  = (double)v;
    ls2[t] = (double)v * (double)v;
    __syncthreads();
    if (t < 64) {
        double s  = (ls[t]  + ls[t + 64])  + (ls[t + 128]  + ls[t + 192]);
        double s2 = (ls2[t] + ls2[t + 64]) + (ls2[t + 128] + ls2[t + 192]);
        p1[blockIdx.x * H2 + t] = s;
        p2[blockIdx.x * H2 + t] = s2;
    }
}

// ---------------------------------------------------------------------------
// K5: pass A = bf16 MFMA bounds, 16 batched loads per 8-tile segment (the
// ONLY change vs the passing R9 kernel — deconfounds R10's dual change);
// worklist pass B = exact fp32; winner via packed u64 LDS atomicMax.
__global__ __launch_bounds__(512)
__attribute__((amdgpu_waves_per_eu(4, 4)))
void k_main(
    const float* __restrict__ a2,
    const float* __restrict__ sc2, const float* __restrict__ sh2,
    const float* __restrict__ W3, const float* __restrict__ b3,
    const unsigned short* __restrict__ w3s, const float* __restrict__ maxw,
    const float* __restrict__ codebook, float* __restrict__ out)
{
    const int t    = threadIdx.x;
    const int wv   = t >> 6;           // wave 0..7
    const int lane = t & 63;
    const int quad = lane >> 4, col = lane & 15;
    const int b0   = blockIdx.x * RROWS;

    __shared__ __align__(16) float h2T[64][RROWS];  // [j][r], 4 KB
    __shared__ float fineS[RROWS][64];              // per-(row, 128-f seg) max
    __shared__ float thrS[RROWS];
    __shared__ unsigned long long best[RROWS];
    __shared__ unsigned short wl[1024];
    __shared__ int wlN;
    __shared__ int rowInd[RROWS];
    __shared__ float maxwS;

    if (t == 0) { maxwS = maxw[0]; wlN = 0; }
    for (int q = t; q < RROWS * 64; q += 512) {
        int j = q >> 4, r = q & 15;
        float v = a2[(b0 + r) * H2 + j];
        h2T[j][r] = fmaxf(fmaf(v, sc2[j], sh2[j]), 0.0f);
    }
    __syncthreads();

    // A fragments (bf16): A[m=col][k=quad*8+jj], k-halves 0/1
    short8 aF0, aF1;
#pragma unroll
    for (int jj = 0; jj < 8; ++jj) {
        aF0[jj] = (short)f2bf(h2T[quad * 8 + jj][col]);
        aF1[jj] = (short)f2bf(h2T[32 + quad * 8 + jj][col]);
    }

    // ---- Pass A: 8 segments x 8 tiles; 16 tile-loads batched per segment ----
    {
        const uint4* wp  = (const uint4*)w3s + (size_t)wv * 8192 + lane;
        const float* b3p = b3 + wv * 1024 + col;
        for (int s = 0; s < 8; ++s) {
            uint4 c[8], d[8];
            float bb[8];
#pragma unroll
            for (int u = 0; u < 8; ++u) {
                c[u]  = wp[u * 128];
                d[u]  = wp[u * 128 + 64];
                bb[u] = b3p[u * 16];
            }
            float rm0 = -1e30f, rm1 = -1e30f, rm2 = -1e30f, rm3 = -1e30f;
#pragma unroll
            for (int u = 0; u < 8; ++u) {
                f32x4 acc = {bb[u], bb[u], bb[u], bb[u]};
                acc = __builtin_amdgcn_mfma_f32_16x16x32_bf16(
                          aF0, *(const short8*)&c[u], acc, 0, 0, 0);
                acc = __builtin_amdgcn_mfma_f32_16x16x32_bf16(
                          aF1, *(const short8*)&d[u], acc, 0, 0, 0);
                rm0 = fmaxf(rm0, acc[0]); rm1 = fmaxf(rm1, acc[1]);
                rm2 = fmaxf(rm2, acc[2]); rm3 = fmaxf(rm3, acc[3]);
            }
#pragma unroll
            for (int off = 1; off < 16; off <<= 1) {
                rm0 = fmaxf(rm0, __shfl_xor(rm0, off));
                rm1 = fmaxf(rm1, __shfl_xor(rm1, off));
                rm2 = fmaxf(rm2, __shfl_xor(rm2, off));
                rm3 = fmaxf(rm3, __shfl_xor(rm3, off));
            }
            if (col == 0) {
                const int seg = wv * 8 + s;
                fineS[quad * 4 + 0][seg] = rm0;
                fineS[quad * 4 + 1][seg] = rm1;
                fineS[quad * 4 + 2][seg] = rm2;
                fineS[quad * 4 + 3][seg] = rm3;
            }
            wp += 1024; b3p += 128;
        }
    }
    __syncthreads();

    // ---- Thresholds (rigorous bf16 margin) ----
    if (t < RROWS) {
        float S = 0.0f;
        for (int j = 0; j < 64; ++j) S += fabsf(h2T[j][t]);
        float gm = -1e30f;
        for (int s = 0; s < 64; ++s) gm = fmaxf(gm, fineS[t][s]);
        float e = S * maxwS * (1.0f / 256.0f);   // |Δlogit| <= S*maxW*2^-8
        thrS[t] = gm - (0.1068f + e + 1e-3f);
        best[t] = 0ull;
    }
    __syncthreads();

    // ---- Worklist of qualifying (row, 128-f seg) cells ----
    for (int c = t; c < RROWS * 64; c += 512) {
        int r = c >> 6, seg = c & 63;
        if (fineS[r][seg] >= thrS[r]) {
            int k = atomicAdd(&wlN, 1);
            wl[k] = (unsigned short)((r << 6) | seg);
        }
    }
    __syncthreads();

    // ---- Pass B: one shared loop; wave per cell; lane per 2 f ----
    const int n = wlN;
    for (int i = wv; i < n; i += 8) {
        const int e   = wl[i];
        const int r   = e >> 6;
        const int seg = e & 63;
        const int f0  = seg * 128 + lane;
        float acc0 = b3[f0], acc1 = b3[f0 + 64];
        const float* wcol = W3 + f0;
#pragma unroll 4
        for (int j = 0; j < 64; ++j) {
            const float h = h2T[j][r];
            acc0 = fmaf(h, wcol[0],  acc0);
            acc1 = fmaf(h, wcol[64], acc1);
            wcol += FEATN;
        }
        const float th = thrS[r];
        if (acc0 >= th) {
            float sc = acc0 + gumbel_g((unsigned)(b0 + r) * (unsigned)FEATN + (unsigned)f0);
            unsigned long long pk = ((unsigned long long)fmono(sc) << 32)
                                  | (unsigned)(FEATN - 1 - f0);
            atomicMax(&best[r], pk);
        }
        if (acc1 >= th) {
            int f1 = f0 + 64;
            float sc = acc1 + gumbel_g((unsigned)(b0 + r) * (unsigned)FEATN + (unsigned)f1);
            unsigned long long pk = ((unsigned long long)fmono(sc) << 32)
                                  | (unsigned)(FEATN - 1 - f1);
            atomicMax(&best[r], pk);
        }
    }
    __syncthreads();
    if (t < RROWS) {
        rowInd[t] = (FEATN - 1 - (int)(best[t] & 0xFFFFFFFFull)) & (FEATN - 1);
    }
    __syncthreads();

    // ---- out[b,:] = codebook[ind,:] ----
    {
        const int rr = t >> 8, tt = t & 255;
        for (int rp = 0; rp < RROWS / 2; ++rp) {
            const int r = rp * 2 + rr;
            const int ind = rowInd[r];
            const float4* src = (const float4*)(codebook + (size_t)ind * FDIM);
            float4*       dst = (float4*)(out + (size_t)(b0 + r) * FDIM);
            dst[tt] = src[tt];
        }
    }
}

// ---------------------------------------------------------------------------
extern "C" void kernel_launch(void* const* d_in, const int* in_sizes, int n_in,
                              void* d_out, int out_size, void* d_ws, size_t ws_size,
                              hipStream_t stream)
{
    const float* x   = (const float*)d_in[0];
    const float* y   = (const float*)d_in[1];
    const float* W1  = (const float*)d_in[2];
    const float* b1  = (const float*)d_in[3];
    const float* g1  = (const float*)d_in[4];
    const float* be1 = (const float*)d_in[5];
    const float* W2  = (const float*)d_in[6];
    const float* b2  = (const float*)d_in[7];
    const float* g2  = (const float*)d_in[8];
    const float* be2 = (const float*)d_in[9];
    const float* W3  = (const float*)d_in[10];
    const float* b3  = (const float*)d_in[11];
    const float* cb  = (const float*)d_in[12];
    float* out = (float*)d_out;

    float* ws  = (float*)d_ws;
    float* a1  = ws;                          // 8 MB
    float* a2  = a1 + B_ROWS * H1;            // 2 MB
    float* sc1 = a2 + B_ROWS * H2;
    float* sh1 = sc1 + H1;
    float* sc2 = sh1 + H1;
    float* sh2 = sc2 + H2;
    double* p1 = (double*)(sh2 + H2);         // 1 MB
    double* p2 = p1 + A2BLKS * H2;            // 1 MB
    unsigned short* w3s = (unsigned short*)(p2 + A2BLKS * H2);  // 1 MB bf16
    float* maxw = (float*)(w3s + NTILE * 2 * 64 * 8);           // 1 f32

    hipMemsetAsync(maxw, 0, 4, stream);
    k_a1    <<<A1BLKS + CONVBLKS, 256, 0, stream>>>(x, y, W1, b1, W3,
                                                    a1, p1, p2, w3s, maxw);
    k_stats2<<<H1, 256, 0, stream>>>(p1, p2, A1BLKS, H1, g1, be1, sc1, sh1);
    k_a2    <<<A2BLKS, 256, 0, stream>>>(a1, sc1, sh1, W2, b2, a2, p1, p2);
    k_stats2<<<H2, 256, 0, stream>>>(p1, p2, A2BLKS, H2, g2, be2, sc2, sh2);
    k_main  <<<B_ROWS / RROWS, 512, 0, stream>>>(a2, sc2, sh2, W3, b3,
                                                 w3s, maxw, cb, out);
}